// Round 2
// baseline (240.460 us; speedup 1.0000x reference)
//
#include <hip/hip_runtime.h>
#include <hip/hip_bf16.h>
#include <math.h>

#define NND 50000
#define NE  600000
#define HD  128
#define NC  10
#define CAP 64          // per-node bucket capacity (max indeg ~40 for this graph)
#define SCATB 256       // scatter blocks (grid-stride over edges, FIRST in k_front)
#define GEMMB 782       // gemm blocks (782*64 = 50048 rows)
#define LOSSB 2344      // edge blocks (2344*256 >= NE)

typedef unsigned short ushort_t;
typedef unsigned char uchar_t;
typedef __attribute__((ext_vector_type(8))) short short8;
typedef __attribute__((ext_vector_type(4))) float f32x4;

__device__ __forceinline__ float bf2f(unsigned short u) {
  return __uint_as_float(((unsigned int)u) << 16);
}
__device__ __forceinline__ unsigned short f2bf(float f) {
  __hip_bfloat16 h = __float2bfloat16(f);  // RNE
  return *(unsigned short*)&h;
}

// convert 8 consecutive fp32 at p into a bf16 short8 fragment
__device__ __forceinline__ short8 f2bf8(const float* __restrict__ p) {
  float4 x0 = *(const float4*)p;
  float4 x1 = *(const float4*)(p + 4);
  short8 v;
  v[0] = (short)f2bf(x0.x); v[1] = (short)f2bf(x0.y);
  v[2] = (short)f2bf(x0.z); v[3] = (short)f2bf(x0.w);
  v[4] = (short)f2bf(x1.x); v[5] = (short)f2bf(x1.y);
  v[6] = (short)f2bf(x1.z); v[7] = (short)f2bf(x1.w);
  return v;
}

// ---------------- shared GEMM body: stages B fragments from fp32 W[128][128] itself ----------------
// Fragment layout (HW-verified): Bs[((nt*4+t)*64+lane)*8+j] = bf16(W[nt*16+(lane&15)][t*32+((lane>>4)&3)*8+j])
template <bool FP32IN>
__device__ __forceinline__ void gemm_body_w(const void* __restrict__ Xv,
                                            const float* __restrict__ W,
                                            const float* __restrict__ b,
                                            ushort_t* __restrict__ Y,
                                            ushort_t* Bs, int bid, int tid) {
  for (int idx = tid; idx < 2048; idx += 256) {
    int g = idx >> 6, lane = idx & 63;
    int nt = g >> 2, t = g & 3;
    int n = nt * 16 + (lane & 15), q = (lane >> 4) & 3;
    *(short8*)&Bs[idx * 8] = f2bf8(&W[n * HD + t * 32 + q * 8]);
  }
  __syncthreads();
  int w = tid >> 6, lane = tid & 63;
  int m = lane & 15, q = lane >> 4;
  int rowbase = bid * 64 + w * 16;
  int rm = rowbase + m; if (rm >= NND) rm = NND - 1;
  short8 a[4];
  if (FP32IN) {
    const float* X = (const float*)Xv;
    #pragma unroll
    for (int t = 0; t < 4; t++)
      a[t] = f2bf8(&X[(long)rm * HD + t * 32 + q * 8]);
  } else {
    const ushort_t* X = (const ushort_t*)Xv;
    #pragma unroll
    for (int t = 0; t < 4; t++)
      a[t] = *(const short8*)&X[(long)rm * HD + t * 32 + q * 8];
  }
  #pragma unroll
  for (int nt = 0; nt < 8; nt++) {
    f32x4 acc = {0.f, 0.f, 0.f, 0.f};
    #pragma unroll
    for (int t = 0; t < 4; t++) {
      short8 bf = *(const short8*)&Bs[((nt * 4 + t) * 64 + lane) * 8];
      acc = __builtin_amdgcn_mfma_f32_16x16x32_bf16(a[t], bf, acc, 0, 0, 0);
    }
    float bias = b[nt * 16 + m];
    #pragma unroll
    for (int reg = 0; reg < 4; reg++) {
      int r = rowbase + q * 4 + reg;
      if (r < NND) Y[(long)r * HD + nt * 16 + m] = f2bf(acc[reg] + bias);
    }
  }
}

// ---------------- front: global-atomic bucket scatter + row-degree | gemm1 ----------------
// slot = atomicAdd(pos[col]) (pos doubles as indeg); deg[row]++ (for dinv).
__global__ __launch_bounds__(256) void k_front(const int* __restrict__ row,
                                               const int* __restrict__ col,
                                               int* __restrict__ pos,
                                               int* __restrict__ deg,
                                               int* __restrict__ srcs,
                                               const float* __restrict__ features,
                                               const float* __restrict__ W1,
                                               const float* __restrict__ b1,
                                               ushort_t* __restrict__ Y,
                                               float* __restrict__ out) {
  __shared__ ushort_t Bs[16384];
  int tid = threadIdx.x, bb = blockIdx.x;
  if (bb < SCATB) {
    if (bb == 0 && tid == 0) out[0] = 0.f;  // loss accumulator for k_edge
    int stride = SCATB * 256;
    for (int e = bb * 256 + tid; e < NE; e += stride) {
      int c = col[e], r = row[e];
      int slot = atomicAdd(&pos[c], 1);
      if (slot < CAP) srcs[(size_t)c * CAP + slot] = r;
      atomicAdd(&deg[r], 1);
    }
  } else {
    gemm_body_w<true>((const void*)features, W1, b1, Y, Bs, bb - SCATB, tid);
  }
}

// ---------------- aggregation (128-wide, conv1): O[i]=dinv_i^2*H[i]+sum dinv_s*dinv_i*H[s] ----------
__global__ __launch_bounds__(256) void k_aggr(const ushort_t* __restrict__ H,
                                              const int* __restrict__ srcs,
                                              const int* __restrict__ pos,
                                              const int* __restrict__ deg,
                                              ushort_t* __restrict__ O) {
  int g = threadIdx.x >> 5, lane = threadIdx.x & 31;
  int half = lane >> 4;
  int fl = (lane & 15) * 8;
  int node = blockIdx.x * 8 + g;
  if (node >= NND) return;
  float di = rsqrtf(1.0f + (float)deg[node]);
  short8 hv = *(const short8*)&H[(long)node * HD + fl];
  float acc[8];
  float sw = (half == 0) ? di * di : 0.0f;
  #pragma unroll
  for (int j = 0; j < 8; j++) acc[j] = sw * bf2f((unsigned short)hv[j]);
  int cnt = pos[node]; if (cnt > CAP) cnt = CAP;
  const int* nb = &srcs[(long)node * CAP];
  for (int base = 0; base < cnt; base += 32) {
    int m = cnt - base; if (m > 32) m = 32;
    int sl = 0; float wl = 0.f;
    if (lane < m) { sl = nb[base + lane]; wl = di * rsqrtf(1.0f + (float)deg[sl]); }
    int iters = (m + 1) >> 1;
    int u = 0;
    for (; u + 1 < iters; u += 2) {
      int t0 = 2 * u + half, t1 = t0 + 2;
      int s0 = __shfl(sl, t0 & 31, 32); float w0 = __shfl(wl, t0 & 31, 32);
      int s1 = __shfl(sl, t1 & 31, 32); float w1 = __shfl(wl, t1 & 31, 32);
      short8 h0 = *(const short8*)&H[(long)s0 * HD + fl];
      short8 h1 = *(const short8*)&H[(long)s1 * HD + fl];
      #pragma unroll
      for (int j = 0; j < 8; j++) acc[j] += w0 * bf2f((unsigned short)h0[j]);
      #pragma unroll
      for (int j = 0; j < 8; j++) acc[j] += w1 * bf2f((unsigned short)h1[j]);
    }
    if (u < iters) {
      int t = 2 * u + half;
      int s = __shfl(sl, t & 31, 32); float w = __shfl(wl, t & 31, 32);
      short8 hs = *(const short8*)&H[(long)s * HD + fl];
      #pragma unroll
      for (int j = 0; j < 8; j++) acc[j] += w * bf2f((unsigned short)hs[j]);
    }
  }
  #pragma unroll
  for (int j = 0; j < 8; j++) acc[j] += __shfl(acc[j], (lane & 15) + 16, 32);
  if (half == 0) {
    short8 r;
    #pragma unroll
    for (int j = 0; j < 8; j++) r[j] = (short)f2bf(acc[j]);
    *(short8*)&O[(long)node * HD + fl] = r;
  }
}

// ---------------- conv2 GEMM fused with projection: Q[r][0:12]=H2g@Wl^T, Q[r][12:24]=H2g@Wc^T ----
// H2g = X@W2^T + b2 kept per-wave in an LDS transpose tile. W2/Wfc converted from fp32 in-kernel.
__global__ __launch_bounds__(256) void k_gemm2q(const ushort_t* __restrict__ X,
                                                const float* __restrict__ W2,
                                                const float* __restrict__ b,
                                                const float* __restrict__ Wfc,
                                                ushort_t* __restrict__ Q) {
  __shared__ ushort_t Bs[16384];          // 32 KB W2 fragments
  __shared__ ushort_t Ts[4 * 16 * 136];   // 17 KB per-wave transpose tiles (pad 136 vs 128)
  int tid = threadIdx.x;
  for (int idx = tid; idx < 2048; idx += 256) {
    int g = idx >> 6, lane2 = idx & 63;
    int nt = g >> 2, t = g & 3;
    int n2 = nt * 16 + (lane2 & 15), q2 = (lane2 >> 4) & 3;
    *(short8*)&Bs[idx * 8] = f2bf8(&W2[n2 * HD + t * 32 + q2 * 8]);
  }
  __syncthreads();
  int w = tid >> 6, lane = tid & 63;
  int m = lane & 15, q = lane >> 4;
  int rowbase = blockIdx.x * 64 + w * 16;
  int rm = rowbase + m; if (rm >= NND) rm = NND - 1;
  short8 a[4];
  #pragma unroll
  for (int t = 0; t < 4; t++)
    a[t] = *(const short8*)&X[(long)rm * HD + t * 32 + q * 8];
  ushort_t* Tw = &Ts[w * 2176];
  #pragma unroll
  for (int nt = 0; nt < 8; nt++) {
    f32x4 acc = {0.f, 0.f, 0.f, 0.f};
    #pragma unroll
    for (int t = 0; t < 4; t++) {
      short8 bf = *(const short8*)&Bs[((nt * 4 + t) * 64 + lane) * 8];
      acc = __builtin_amdgcn_mfma_f32_16x16x32_bf16(a[t], bf, acc, 0, 0, 0);
    }
    float bias = b[nt * 16 + m];
    #pragma unroll
    for (int reg = 0; reg < 4; reg++)
      Tw[(q * 4 + reg) * 136 + nt * 16 + m] = f2bf(acc[reg] + bias);
  }
  // read back as A-fragments (row = m, k = t*32+q*8) — within-wave dep, lgkmcnt only
  short8 a2[4];
  #pragma unroll
  for (int t = 0; t < 4; t++)
    a2[t] = *(const short8*)&Tw[m * 136 + t * 32 + q * 8];
  // projection fragments straight from Wfc fp32 (zeros for class rows >= NC)
  f32x4 aL = {0.f, 0.f, 0.f, 0.f}, aR = {0.f, 0.f, 0.f, 0.f};
  #pragma unroll
  for (int t = 0; t < 8; t++) {
    short8 bv = {0, 0, 0, 0, 0, 0, 0, 0};
    if (m < NC) bv = f2bf8(&Wfc[m * 256 + t * 32 + q * 8]);
    if (t < 4) aL = __builtin_amdgcn_mfma_f32_16x16x32_bf16(a2[t], bv, aL, 0, 0, 0);
    else       aR = __builtin_amdgcn_mfma_f32_16x16x32_bf16(a2[t & 3], bv, aR, 0, 0, 0);
  }
  if (m < 12) {
    #pragma unroll
    for (int reg = 0; reg < 4; reg++) {
      int r = rowbase + q * 4 + reg;
      if (r < NND) {
        Q[(long)r * 24 + m]      = f2bf(aL[reg]);
        Q[(long)r * 24 + 12 + m] = f2bf(aR[reg]);
      }
    }
  }
}

// ---------------- narrow aggregation over projected rows (48 B/source) ----------------
__global__ __launch_bounds__(256) void k_aggr2(const ushort_t* __restrict__ Q,
                                               const int* __restrict__ srcs,
                                               const int* __restrict__ pos,
                                               const int* __restrict__ deg,
                                               float* __restrict__ Pr,
                                               float* __restrict__ Pc) {
  int g = threadIdx.x >> 5, lane = threadIdx.x & 31;
  int half = lane >> 4;
  int f = lane & 15;               // dword index; f<12 active (24 bf16 = 12 dwords)
  int node = blockIdx.x * 8 + g;
  if (node >= NND) return;
  float di = rsqrtf(1.0f + (float)deg[node]);
  bool act = (f < 12);
  unsigned int qv = act ? *(const unsigned int*)&Q[(long)node * 24 + 2 * f] : 0u;
  float sw = (half == 0) ? di * di : 0.f;
  float a0 = sw * bf2f((ushort_t)(qv & 0xffff));
  float a1 = sw * bf2f((ushort_t)(qv >> 16));
  int cnt = pos[node]; if (cnt > CAP) cnt = CAP;
  const int* nb = &srcs[(long)node * CAP];
  for (int base = 0; base < cnt; base += 32) {
    int m2 = cnt - base; if (m2 > 32) m2 = 32;
    int sl = 0; float wl = 0.f;
    if (lane < m2) { sl = nb[base + lane]; wl = di * rsqrtf(1.0f + (float)deg[sl]); }
    int iters = (m2 + 1) >> 1;
    int u = 0;
    for (; u + 1 < iters; u += 2) {
      int t0 = 2 * u + half, t1 = t0 + 2;
      int s0 = __shfl(sl, t0 & 31, 32); float w0 = __shfl(wl, t0 & 31, 32);
      int s1 = __shfl(sl, t1 & 31, 32); float w1 = __shfl(wl, t1 & 31, 32);
      unsigned int h0 = act ? *(const unsigned int*)&Q[(long)s0 * 24 + 2 * f] : 0u;
      unsigned int h1 = act ? *(const unsigned int*)&Q[(long)s1 * 24 + 2 * f] : 0u;
      a0 += w0 * bf2f((ushort_t)(h0 & 0xffff));
      a1 += w0 * bf2f((ushort_t)(h0 >> 16));
      a0 += w1 * bf2f((ushort_t)(h1 & 0xffff));
      a1 += w1 * bf2f((ushort_t)(h1 >> 16));
    }
    if (u < iters) {
      int t = 2 * u + half;
      int s = __shfl(sl, t & 31, 32); float wv = __shfl(wl, t & 31, 32);
      unsigned int hs = act ? *(const unsigned int*)&Q[(long)s * 24 + 2 * f] : 0u;
      a0 += wv * bf2f((ushort_t)(hs & 0xffff));
      a1 += wv * bf2f((ushort_t)(hs >> 16));
    }
  }
  a0 += __shfl(a0, f + 16, 32);
  a1 += __shfl(a1, f + 16, 32);
  if (half == 0 && act) {
    float2 v; v.x = a0; v.y = a1;
    if (f < 6) *(float2*)&Pr[(long)node * 12 + 2 * f] = v;
    else       *(float2*)&Pc[(long)node * 12 + 2 * (f - 6)] = v;
  }
}

// ---------------- edge: logits[e] = Pr[row]+Pc[col]+bfc; LDS-staged coalesced store; atomic loss --
__global__ __launch_bounds__(256) void k_edge(const float* __restrict__ Pr,
                                              const float* __restrict__ Pc,
                                              const int* __restrict__ row,
                                              const int* __restrict__ col,
                                              const int* __restrict__ label,
                                              const float* __restrict__ bfc,
                                              float* __restrict__ logits,
                                              float* __restrict__ out) {
  __shared__ __align__(16) float S[2560];
  __shared__ float Ls[4];
  int tid = threadIdx.x;
  long e0 = (long)blockIdx.x * 256;
  int e = (int)e0 + tid;
  float lp = 0.f;
  if (e < NE) {
    int r = row[e], c = col[e];
    const float* pr = &Pr[(long)r * 12];
    const float* pc = &Pc[(long)c * 12];
    float4 r0 = *(const float4*)&pr[0];
    float4 r1 = *(const float4*)&pr[4];
    float4 r2 = *(const float4*)&pr[8];
    float4 c0 = *(const float4*)&pc[0];
    float4 c1 = *(const float4*)&pc[4];
    float4 c2 = *(const float4*)&pc[8];
    float p[NC];
    p[0] = r0.x + c0.x + bfc[0]; p[1] = r0.y + c0.y + bfc[1];
    p[2] = r0.z + c0.z + bfc[2]; p[3] = r0.w + c0.w + bfc[3];
    p[4] = r1.x + c1.x + bfc[4]; p[5] = r1.y + c1.y + bfc[5];
    p[6] = r1.z + c1.z + bfc[6]; p[7] = r1.w + c1.w + bfc[7];
    p[8] = r2.x + c2.x + bfc[8]; p[9] = r2.y + c2.y + bfc[9];
    #pragma unroll
    for (int cc = 0; cc < NC; cc++) S[tid * 10 + cc] = p[cc];
    float mx = p[0];
    #pragma unroll
    for (int cc = 1; cc < NC; cc++) mx = fmaxf(mx, p[cc]);
    float se = 0.f;
    #pragma unroll
    for (int cc = 0; cc < NC; cc++) se += __expf(p[cc] - mx);
    int lb = label[e];
    float plb = p[0];
    #pragma unroll
    for (int cc = 1; cc < NC; cc++) plb = (cc == lb) ? p[cc] : plb;
    lp = plb - mx - __logf(se);
  }
  __syncthreads();
  int ve = NE - (int)e0; if (ve > 256) ve = 256;
  int limF4 = ve * 10 / 4;   // ve % 4 == 0 always
  float4* dst = (float4*)&logits[e0 * 10];
  const float4* src4 = (const float4*)S;
  for (int i = tid; i < limF4; i += 256) dst[i] = src4[i];
  #pragma unroll
  for (int off = 32; off > 0; off >>= 1) lp += __shfl_xor(lp, off, 64);
  if ((tid & 63) == 0) Ls[tid >> 6] = lp;
  __syncthreads();
  if (tid == 0)
    atomicAdd(out, -(Ls[0] + Ls[1] + Ls[2] + Ls[3]) / (float)NE);
}

extern "C" void kernel_launch(void* const* d_in, const int* in_sizes, int n_in,
                              void* d_out, int out_size, void* d_ws, size_t ws_size,
                              hipStream_t stream) {
  const float* features = (const float*)d_in[0];
  const float* W1  = (const float*)d_in[1];
  const float* b1  = (const float*)d_in[2];
  const float* W2  = (const float*)d_in[3];
  const float* b2  = (const float*)d_in[4];
  const float* Wfc = (const float*)d_in[5];
  const float* bfc = (const float*)d_in[6];
  const int* row   = (const int*)d_in[7];
  const int* col   = (const int*)d_in[8];
  const int* label = (const int*)d_in[9];
  float* out = (float*)d_out;

  int* pos = (int*)d_ws;                       // 50048 ints (doubles as indeg)
  int* deg = pos + 50048;                      // 50048 ints (row degree)
  int* srcs = deg + 50048;                     // NND*CAP ints, 12.8 MB buckets
  float* Pr = (float*)(srcs + (size_t)NND * CAP);   // 600000 fl (50000 x 12)
  float* Pc = Pr + 600000;                     // 600000 fl
  ushort_t* bufA = (ushort_t*)(Pc + 600000);   // 6.4M bf16
  ushort_t* bufB = bufA + 6400000;             // 6.4M bf16
  ushort_t* Q = bufA;                          // 2.4 MB, reuses bufA (free after aggr1)

  // zero pos+deg (contiguous), then one-pass atomic scatter/degree + gemm1
  hipMemsetAsync(pos, 0, 2 * 50048 * sizeof(int), stream);
  k_front<<<SCATB + GEMMB, 256, 0, stream>>>(row, col, pos, deg, srcs,
                                             features, W1, b1, bufA, out);
  // conv1 aggregate (128-wide)
  k_aggr<<<6250, 256, 0, stream>>>(bufA, srcs, pos, deg, bufB);
  // conv2 GEMM fused with Wfc projection -> Q[50000][24] bf16
  k_gemm2q<<<GEMMB, 256, 0, stream>>>(bufB, W2, b2, Wfc, Q);
  // narrow aggregation of projected rows -> Pr/Pc
  k_aggr2<<<6250, 256, 0, stream>>>(Q, srcs, pos, deg, Pr, Pc);
  // per-edge logits + fused loss (atomic accumulate into out[0])
  k_edge<<<LOSSB, 256, 0, stream>>>(Pr, Pc, row, col, label, bfc, out + 1, out);
}